// Round 1
// baseline (1029.308 us; speedup 1.0000x reference)
//
#include <hip/hip_runtime.h>

#define Bq 2
#define Sq 2048
#define Hq 1024
#define NHq 16
#define HDq 64

typedef __bf16 bf16x8 __attribute__((ext_vector_type(8)));
typedef float f32x4 __attribute__((ext_vector_type(4)));

__device__ __forceinline__ unsigned short f2b(float f) {
  union { float f; unsigned int u; } v; v.f = f;
  unsigned int u = v.u;
  u += 0x7fffu + ((u >> 16) & 1);   // RNE to bf16
  return (unsigned short)(u >> 16);
}

__global__ __launch_bounds__(256) void k_f2bf(const float* __restrict__ in,
                                              unsigned short* __restrict__ out, int n4) {
  int i = blockIdx.x * 256 + threadIdx.x;
  if (i >= n4) return;
  float4 v = ((const float4*)in)[i];
  ushort4 o;
  o.x = f2b(v.x); o.y = f2b(v.y); o.z = f2b(v.z); o.w = f2b(v.w);
  ((ushort4*)out)[i] = o;
}

// C[m][n] = sum_k A[m*lda+k] * B[n*ldb+k]   (both operands K-major, bf16)
// MODE 0: bf16 out -> [B,NH,S,HD] (+bias)     (Q,K projections)
// MODE 1: bf16 out -> [B,NH,HD,S] (+bias)     (V projection, transposed)
// MODE 3: fp32 out -> row-major [.,1024] + bias (out projection)
template<int MODE>
__global__ __launch_bounds__(256) void k_gemm_bt(
    const unsigned short* __restrict__ Abase,
    const unsigned short* __restrict__ Bbase,
    const float* __restrict__ bias,
    void* __restrict__ Cout,
    int Klen, int lda, int ldb)
{
  __shared__ __align__(16) unsigned short As[128 * 32];
  __shared__ __align__(16) unsigned short Bs[128 * 32];

  const int tid = threadIdx.x;
  const int l = tid & 63;
  const int w = tid >> 6;
  const unsigned short* A  = Abase;
  const unsigned short* Bm = Bbase;
  const int row0 = blockIdx.y * 128;
  const int col0 = blockIdx.x * 128;

  const int wm = w & 1, wn = w >> 1;
  const int lrow = l & 15;
  const int lk = (l >> 4) * 8;

  f32x4 acc[4][4] = {};

  for (int kk = 0; kk < Klen; kk += 32) {
    __syncthreads();
#pragma unroll
    for (int c2 = 0; c2 < 2; ++c2) {
      int c = 2 * w + c2;
      int f = c * 512 + l * 8;
      int r = f >> 5, k = f & 31;
      __builtin_amdgcn_global_load_lds(
          (__attribute__((address_space(1))) void*)(A + (size_t)(row0 + r) * lda + kk + k),
          (__attribute__((address_space(3))) void*)(&As[c * 512]), 16, 0, 0);
      __builtin_amdgcn_global_load_lds(
          (__attribute__((address_space(1))) void*)(Bm + (size_t)(col0 + r) * ldb + kk + k),
          (__attribute__((address_space(3))) void*)(&Bs[c * 512]), 16, 0, 0);
    }
    __syncthreads();

    bf16x8 af[4], bfr[4];
#pragma unroll
    for (int mt = 0; mt < 4; ++mt)
      af[mt] = *(const bf16x8*)&As[(wm * 64 + mt * 16 + lrow) * 32 + lk];
#pragma unroll
    for (int nt = 0; nt < 4; ++nt)
      bfr[nt] = *(const bf16x8*)&Bs[(wn * 64 + nt * 16 + lrow) * 32 + lk];
#pragma unroll
    for (int mt = 0; mt < 4; ++mt)
#pragma unroll
      for (int nt = 0; nt < 4; ++nt)
        acc[mt][nt] = __builtin_amdgcn_mfma_f32_16x16x32_bf16(af[mt], bfr[nt], acc[mt][nt], 0, 0, 0);
  }

  const int quad = l >> 4;
#pragma unroll
  for (int mt = 0; mt < 4; ++mt) {
#pragma unroll
    for (int nt = 0; nt < 4; ++nt) {
#pragma unroll
      for (int r = 0; r < 4; ++r) {
        int grow = row0 + wm * 64 + mt * 16 + quad * 4 + r;
        int gcol = col0 + wn * 64 + nt * 16 + lrow;
        float v = acc[mt][nt][r];
        if constexpr (MODE == 0) {
          v += bias[gcol];
          int b = grow >> 11, s = grow & 2047;
          int nh = gcol >> 6, hd = gcol & 63;
          ((unsigned short*)Cout)[((size_t)(b * NHq + nh) * Sq + s) * HDq + hd] = f2b(v);
        } else if constexpr (MODE == 1) {
          v += bias[gcol];
          int b = grow >> 11, s = grow & 2047;
          int nh = gcol >> 6, hd = gcol & 63;
          ((unsigned short*)Cout)[((size_t)(b * NHq + nh) * HDq + hd) * Sq + s] = f2b(v);
        } else {
          ((float*)Cout)[(size_t)grow * Hq + gcol] = v + bias[gcol];
        }
      }
    }
  }
}

// Fused attention: per block = (head z, 16 query rows).
// Swapped-operand QK^T (D = S^T tile -> lane owns query row l&15, 4 consecutive j per reg),
// full row of scores in 128 VGPRs, register softmax, attn written fp32 from regs,
// unnormalized e -> bf16 LDS P (m97-style [ks][16][32] layout + 16B XOR swizzle),
// PV from LDS a-frags + L2-resident V^T b-frags, output scaled by invsum.
__global__ __launch_bounds__(256, 2) void k_attn_fused(
    const unsigned short* __restrict__ Qh,   // [32][2048][64] bf16
    const unsigned short* __restrict__ Kh,   // [32][2048][64] bf16
    const unsigned short* __restrict__ Vt,   // [32][64][2048] bf16
    const int* __restrict__ mask,            // [B][1][2048][2048]
    float* __restrict__ attn,                // [32][2048][2048] fp32 (output)
    unsigned short* __restrict__ ctx)        // [B][2048][1024] bf16
{
  __shared__ __align__(16) unsigned short Pl[64 * 16 * 32];  // 64 KB
  __shared__ float redA[4][16];
  __shared__ float redB[4][16];

  const int tid = threadIdx.x;
  const int l = tid & 63;
  const int w = tid >> 6;          // wave 0..3, owns columns [w*512, w*512+512)
  const int row = l & 15;          // query row within block (QK^T D col / PV A row / V hd col)
  const int q = l >> 4;            // quad
  const int z = blockIdx.y;
  const int b = z >> 4, nh = z & 15;
  const int i0 = blockIdx.x * 16;

  const unsigned short* Qz = Qh + ((size_t)z * Sq + i0) * HDq;
  const unsigned short* Kz = Kh + (size_t)z * Sq * HDq;

  // Q b-frags: B[k=hd][col=row] = Q[i0+row][hd], 8 consecutive hd per lane
  bf16x8 bq0 = *(const bf16x8*)&Qz[row * HDq + q * 8];
  bf16x8 bq1 = *(const bf16x8*)&Qz[row * HDq + 32 + q * 8];

  f32x4 sc[32];
#pragma unroll
  for (int t = 0; t < 32; ++t) {
    int j0 = w * 512 + t * 16;
    // K a-frags: A[m=j][k=hd] = K[j0+row_m][hd]; here a-row = l&15 is the j index
    bf16x8 a0 = *(const bf16x8*)&Kz[(size_t)(j0 + row) * HDq + q * 8];
    bf16x8 a1 = *(const bf16x8*)&Kz[(size_t)(j0 + row) * HDq + 32 + q * 8];
    f32x4 acc = {};
    acc = __builtin_amdgcn_mfma_f32_16x16x32_bf16(a0, bq0, acc, 0, 0, 0);
    acc = __builtin_amdgcn_mfma_f32_16x16x32_bf16(a1, bq1, acc, 0, 0, 0);
    sc[t] = acc;   // sc[t][r] = S[i0+row][j0 + q*4 + r]
  }

  // mask + scale (reference: scores/8 then where(mask==0, -1e9))
  const int* mrow = mask + (size_t)b * Sq * Sq + (size_t)(i0 + row) * Sq;
#pragma unroll
  for (int t = 0; t < 32; ++t) {
    int j0 = w * 512 + t * 16;
    int4 mv = *(const int4*)&mrow[j0 + q * 4];
    sc[t][0] = mv.x ? sc[t][0] * 0.125f : -1e9f;
    sc[t][1] = mv.y ? sc[t][1] * 0.125f : -1e9f;
    sc[t][2] = mv.z ? sc[t][2] * 0.125f : -1e9f;
    sc[t][3] = mv.w ? sc[t][3] * 0.125f : -1e9f;
  }

  // row max: per-lane over 128 vals, then lanes {l, l^16, l^32} share a row, then cross-wave
  float m = -3.4e38f;
#pragma unroll
  for (int t = 0; t < 32; ++t)
    m = fmaxf(m, fmaxf(fmaxf(sc[t][0], sc[t][1]), fmaxf(sc[t][2], sc[t][3])));
  m = fmaxf(m, __shfl_xor(m, 16));
  m = fmaxf(m, __shfl_xor(m, 32));
  if (l < 16) redA[w][l] = m;
  __syncthreads();
  m = fmaxf(fmaxf(redA[0][row], redA[1][row]), fmaxf(redA[2][row], redA[3][row]));

  // exp + row sum
  float s = 0.f;
#pragma unroll
  for (int t = 0; t < 32; ++t) {
#pragma unroll
    for (int r = 0; r < 4; ++r) {
      float e = __expf(sc[t][r] - m);
      sc[t][r] = e;
      s += e;
    }
  }
  s += __shfl_xor(s, 16);
  s += __shfl_xor(s, 32);
  if (l < 16) redB[w][l] = s;
  __syncthreads();
  float inv = 1.0f / (redB[0][row] + redB[1][row] + redB[2][row] + redB[3][row]);

  // write attn (fp32, normalized) + stage unnormalized e as bf16 P into LDS
  float* attnz = attn + (size_t)z * Sq * Sq + (size_t)(i0 + row) * Sq;
#pragma unroll
  for (int t = 0; t < 32; ++t) {
    int j0 = w * 512 + t * 16;
    float4 wv;
    wv.x = sc[t][0] * inv; wv.y = sc[t][1] * inv;
    wv.z = sc[t][2] * inv; wv.w = sc[t][3] * inv;
    *(float4*)&attnz[j0 + q * 4] = wv;
    ushort4 pb;
    pb.x = f2b(sc[t][0]); pb.y = f2b(sc[t][1]);
    pb.z = f2b(sc[t][2]); pb.w = f2b(sc[t][3]);
    // P layout: [ks=j>>5][row][jw=j&31] bf16, XOR-swizzled in 16B units by row&3
    int ks = j0 >> 5;
    int b5 = (j0 >> 4) & 1;
    int off = (ks * 16 + row) * 64 + (((b5 << 5) + (q << 3)) ^ ((row & 3) << 4));
    *(ushort4*)((char*)Pl + off) = pb;
  }
  __syncthreads();

  // PV: wave w computes ctx[16 rows][hd = w*16 .. w*16+15], K = 2048
  const unsigned short* Vw = Vt + (size_t)z * HDq * Sq + (size_t)(w * 16 + row) * Sq;
  f32x4 acc = {};
#pragma unroll 4
  for (int ks = 0; ks < 64; ++ks) {
    int off = (ks * 16 + row) * 64 + ((q << 4) ^ ((row & 3) << 4));
    bf16x8 af = *(const bf16x8*)((const char*)Pl + off);          // P[row][ks*32 + q*8 ..]
    bf16x8 bf = *(const bf16x8*)&Vw[ks * 32 + q * 8];             // V^T[hd][ks*32 + q*8 ..]
    acc = __builtin_amdgcn_mfma_f32_16x16x32_bf16(af, bf, acc, 0, 0, 0);
  }

#pragma unroll
  for (int r = 0; r < 4; ++r) {
    int srow = i0 + q * 4 + r;
    float iv = __shfl(inv, q * 4 + r);   // lane (q*4+r) holds invsum of row q*4+r
    ctx[((size_t)(b * Sq + srow)) * Hq + nh * HDq + w * 16 + row] = f2b(acc[r] * iv);
  }
}

extern "C" void kernel_launch(void* const* d_in, const int* in_sizes, int n_in,
                              void* d_out, int out_size, void* d_ws, size_t ws_size,
                              hipStream_t stream) {
  const float* query = (const float*)d_in[0];
  const float* key_  = (const float*)d_in[1];
  const float* value = (const float*)d_in[2];
  const int*   mask  = (const int*)d_in[3];
  const float* Wq = (const float*)d_in[4];
  const float* bq = (const float*)d_in[5];
  const float* Wk = (const float*)d_in[6];
  const float* bk = (const float*)d_in[7];
  const float* Wv = (const float*)d_in[8];
  const float* bv = (const float*)d_in[9];
  const float* Wo = (const float*)d_in[10];
  const float* bo = (const float*)d_in[11];

  unsigned short* Xq  = (unsigned short*)d_ws;           // 4096*1024
  unsigned short* Xk  = Xq  + (size_t)4096 * 1024;
  unsigned short* Xv  = Xk  + (size_t)4096 * 1024;
  unsigned short* Wqb = Xv  + (size_t)4096 * 1024;       // 1024*1024 each
  unsigned short* Wkb = Wqb + (size_t)1024 * 1024;
  unsigned short* Wvb = Wkb + (size_t)1024 * 1024;
  unsigned short* Wob = Wvb + (size_t)1024 * 1024;
  unsigned short* Qh  = Wob + (size_t)1024 * 1024;       // [32][2048][64]
  unsigned short* Kh  = Qh  + (size_t)32 * 2048 * 64;
  unsigned short* Vt  = Kh  + (size_t)32 * 2048 * 64;    // [32][64][2048]
  unsigned short* ctx = Vt  + (size_t)32 * 2048 * 64;    // [4096][1024]

  float* outp = (float*)d_out;                           // [4096][1024]
  float* attn = outp + (size_t)4096 * 1024;              // [32][2048][2048]

  // fp32 -> bf16 conversions
  k_f2bf<<<4096, 256, 0, stream>>>(query, Xq, 1048576);
  k_f2bf<<<4096, 256, 0, stream>>>(key_,  Xk, 1048576);
  k_f2bf<<<4096, 256, 0, stream>>>(value, Xv, 1048576);
  k_f2bf<<<1024, 256, 0, stream>>>(Wq, Wqb, 262144);
  k_f2bf<<<1024, 256, 0, stream>>>(Wk, Wkb, 262144);
  k_f2bf<<<1024, 256, 0, stream>>>(Wv, Wvb, 262144);
  k_f2bf<<<1024, 256, 0, stream>>>(Wo, Wob, 262144);

  // projections: [4096x1024] = X @ W^T + b
  dim3 gproj(8, 32, 1);
  k_gemm_bt<0><<<gproj, 256, 0, stream>>>(Xq, Wqb, bq, Qh, 1024, 1024, 1024);
  k_gemm_bt<0><<<gproj, 256, 0, stream>>>(Xk, Wkb, bk, Kh, 1024, 1024, 1024);
  k_gemm_bt<1><<<gproj, 256, 0, stream>>>(Xv, Wvb, bv, Vt, 1024, 1024, 1024);

  // fused QK^T + mask + softmax + attn-write + PV
  dim3 gattn(128, 32, 1);
  k_attn_fused<<<gattn, 256, 0, stream>>>(Qh, Kh, Vt, mask, attn, ctx);

  // output = ctx @ Wo^T + bo  (fp32 into d_out)
  dim3 gout(8, 32, 1);
  k_gemm_bt<3><<<gout, 256, 0, stream>>>(ctx, Wob, bo, outp, 1024, 1024, 1024);
}